// Round 15
// baseline (302.636 us; speedup 1.0000x reference)
//
#include <hip/hip_runtime.h>

#define BB 4
#define SS 2048
#define DD 64
#define HH 16
#define HDD 4
#define NBH (BB*HH)          // 64 (b,h) pairs
#define NROWS (BB*SS)        // 8192
#define NQ (NBH*SS)          // 131072 query rows
#define LOG2E_HALF 0.7213475204444817f  // log2(e)*0.5 (1/sqrt(HD) folded into K)

// native 2-wide fp32 vector: compiler lowers fma on this to v_pk_fma_f32
// (gfx90a+ packed-FP32), inserting required hazard wait-states itself.
typedef float f32x2 __attribute__((ext_vector_type(2)));

#define QR 2                         // query rows per thread
#define QTN (SS/(256*QR))            // 4 q-tiles per bh
#define NGRP (NBH*QTN)               // 256 combine groups

// ---------------- Kernel 1: QKV projection + ReLU (R10 exact) --------------
// Also zeroes the 256 group counters (block 0) -- same-stream kernel
// ordering makes them visible to the attention kernel.
__global__ __launch_bounds__(256) void qkv_kernel(
    const float* __restrict__ x,
    const float* __restrict__ Wq, const float* __restrict__ bq,
    const float* __restrict__ Wk, const float* __restrict__ bk,
    const float* __restrict__ Wv, const float* __restrict__ bv,
    float* __restrict__ Q, float* __restrict__ KV,
    unsigned int* __restrict__ cnt)
{
    if (blockIdx.x == 0) cnt[threadIdx.x] = 0u;   // NGRP == blockDim == 256

    __shared__ float xs[4 * 64];
    const int tid = threadIdx.x;
    const int row0 = blockIdx.x * 4;

    xs[tid] = x[(size_t)row0 * 64 + tid];
    __syncthreads();

    const int r = tid >> 6;
    const int c = tid & 63;
    const int row = row0 + r;
    const int b = row >> 11;
    const int s = row & (SS - 1);
    const float* xr = &xs[r * 64];

    float aq = bq[c], ak = bk[c], av = bv[c];
    #pragma unroll 16
    for (int k = 0; k < 64; ++k) {
        const float xv = xr[k];
        aq = fmaf(xv, Wq[k * 64 + c], aq);
        ak = fmaf(xv, Wk[k * 64 + c], ak);
        av = fmaf(xv, Wv[k * 64 + c], av);
    }
    aq = fmaxf(aq, 0.0f);
    ak = fmaxf(ak, 0.0f) * LOG2E_HALF;   // fold softmax scale+log2e into K
    av = fmaxf(av, 0.0f);

    const int h = c >> 2, hd = c & 3;
    const size_t bhs = ((size_t)(b * HH + h) * SS + s);
    Q[bhs * 4 + hd] = aq;

    const int p = s >> 1, po = s & 1;
    const size_t pb = ((size_t)(b * HH + h) * (SS / 2) + p) * 16;
    KV[pb + hd * 2 + po] = ak;
    KV[pb + 8 + hd * 2 + po] = av;
}

// ---------------- Kernel 2: attention + last-block combine -----------------
// Main loop = R10 exact (LDS-staged KV chunk, broadcast reads, packed fp32,
// hardware v_exp_f32, no max-subtraction).
// Epilogue: store partial acc/sum; release + atomic-increment this (bh,qt)
// group's counter; the KSPLIT'th arriver (any block -- math is fixed-order,
// so deterministic) acquires, combines all partials, applies softmax +
// residual, writes y, and emits per-channel BN sum/sumsq into part2
// (16 slots per channel: slot = b*4 + qt). No barrier, no co-residency
// assumption -- pure reduction dependency (G16-safe).
template<int KSPLIT>
__global__ __launch_bounds__(256) void attn_kernel(
    const float* __restrict__ Qb, const float* __restrict__ KVb,
    const float* __restrict__ x, float* __restrict__ y,
    float* __restrict__ accS, float* __restrict__ sumS,
    float* __restrict__ part2, unsigned int* __restrict__ cnt)
{
    constexpr int PAIRS = SS / 2 / KSPLIT;
    __shared__ float4 kvs4[PAIRS * 4];       // PAIRS*64 bytes (8 KB at KS=8)
    __shared__ float rr[4][8];
    __shared__ unsigned int oldv;
    const f32x2* kvs = (const f32x2*)kvs4;

    const int tid = threadIdx.x;
    int blk = blockIdx.x;
    const int ks = blk / (NBH * QTN);
    blk -= ks * (NBH * QTN);
    const int bh = blk / QTN;
    const int qt = blk - bh * QTN;

    const float4* kvg = (const float4*)(KVb + ((size_t)bh * (SS / 2) + (size_t)ks * PAIRS) * 16);
    #pragma unroll
    for (int i = 0; i < PAIRS * 4 / 256; ++i)
        kvs4[i * 256 + tid] = kvg[i * 256 + tid];

    f32x2 qx[QR], qy[QR], qz[QR], qw[QR];
    #pragma unroll
    for (int r = 0; r < QR; ++r) {
        const int qrow = qt * (256 * QR) + r * 256 + tid;
        const float4 q = ((const float4*)Qb)[(size_t)bh * SS + qrow];
        qx[r] = {q.x, q.x}; qy[r] = {q.y, q.y};
        qz[r] = {q.z, q.z}; qw[r] = {q.w, q.w};
    }

    f32x2 acx[QR], acy[QR], acz[QR], acw[QR], sm[QR];
    #pragma unroll
    for (int r = 0; r < QR; ++r) {
        acx[r] = {0.f, 0.f}; acy[r] = {0.f, 0.f};
        acz[r] = {0.f, 0.f}; acw[r] = {0.f, 0.f};
        sm[r] = {0.f, 0.f};
    }

    __syncthreads();

    #pragma unroll 2
    for (int j = 0; j < PAIRS; ++j) {
        const f32x2 kx = kvs[j * 8 + 0];   // broadcast LDS reads
        const f32x2 ky = kvs[j * 8 + 1];
        const f32x2 kz = kvs[j * 8 + 2];
        const f32x2 kw = kvs[j * 8 + 3];
        const f32x2 vx = kvs[j * 8 + 4];
        const f32x2 vy = kvs[j * 8 + 5];
        const f32x2 vz = kvs[j * 8 + 6];
        const f32x2 vw = kvs[j * 8 + 7];
        #pragma unroll
        for (int r = 0; r < QR; ++r) {
            f32x2 s = qx[r] * kx;
            s = __builtin_elementwise_fma(qy[r], ky, s);
            s = __builtin_elementwise_fma(qz[r], kz, s);
            s = __builtin_elementwise_fma(qw[r], kw, s);
            f32x2 e;
            e.x = __builtin_amdgcn_exp2f(s.x);
            e.y = __builtin_amdgcn_exp2f(s.y);
            sm[r] += e;
            acx[r] = __builtin_elementwise_fma(e, vx, acx[r]);
            acy[r] = __builtin_elementwise_fma(e, vy, acy[r]);
            acz[r] = __builtin_elementwise_fma(e, vz, acz[r]);
            acw[r] = __builtin_elementwise_fma(e, vw, acw[r]);
        }
    }

    // ---- store this block's partials ----
    #pragma unroll
    for (int r = 0; r < QR; ++r) {
        const int qrow = qt * (256 * QR) + r * 256 + tid;
        const size_t qi = (size_t)ks * NQ + (size_t)bh * SS + qrow;
        float4 acc = {acx[r].x + acx[r].y, acy[r].x + acy[r].y,
                      acz[r].x + acz[r].y, acw[r].x + acw[r].y};
        ((float4*)accS)[qi] = acc;
        sumS[qi] = sm[r].x + sm[r].y;
    }

    // ---- release + arrive (canonical last-block-reduction pattern) ----
    __threadfence();
    __syncthreads();
    if (tid == 0)
        oldv = __hip_atomic_fetch_add(&cnt[bh * QTN + qt], 1u,
                                      __ATOMIC_ACQ_REL, __HIP_MEMORY_SCOPE_AGENT);
    __syncthreads();
    if (oldv != (unsigned)(KSPLIT - 1)) return;   // block-uniform branch

    // ---- this block is last for its group: combine + residual + BN ----
    __threadfence();                              // acquire side
    const int b = bh >> 4, h = bh & 15;
    float vv[8] = {0.f, 0.f, 0.f, 0.f, 0.f, 0.f, 0.f, 0.f};
    #pragma unroll
    for (int r = 0; r < QR; ++r) {
        const int qrow = qt * (256 * QR) + r * 256 + tid;
        const size_t qbase = (size_t)bh * SS + qrow;
        float4 a = ((const float4*)accS)[qbase];
        float s = sumS[qbase];
        #pragma unroll
        for (int k = 1; k < KSPLIT; ++k) {
            const float4 a2 = ((const float4*)accS)[(size_t)k * NQ + qbase];
            a.x += a2.x; a.y += a2.y; a.z += a2.z; a.w += a2.w;
            s += sumS[(size_t)k * NQ + qbase];
        }
        const float inv = 1.0f / s;
        const size_t o = ((size_t)(b * SS + qrow)) * DD + h * HDD;
        const float4 xr = *(const float4*)(x + o);
        float4 out;
        out.x = fmaf(a.x, inv, xr.x);
        out.y = fmaf(a.y, inv, xr.y);
        out.z = fmaf(a.z, inv, xr.z);
        out.w = fmaf(a.w, inv, xr.w);
        *(float4*)(y + o) = out;
        vv[0] += out.x; vv[1] += out.y; vv[2] += out.z; vv[3] += out.w;
        vv[4] += out.x * out.x; vv[5] += out.y * out.y;
        vv[6] += out.z * out.z; vv[7] += out.w * out.w;
    }
    #pragma unroll
    for (int i = 0; i < 8; ++i) {
        float t = vv[i];
        for (int off = 32; off > 0; off >>= 1) t += __shfl_down(t, off);
        vv[i] = t;
    }
    const int wid = tid >> 6;
    if ((tid & 63) == 0) {
        #pragma unroll
        for (int i = 0; i < 8; ++i) rr[wid][i] = vv[i];
    }
    __syncthreads();
    if (tid < 8) {
        const float t = rr[0][tid] + rr[1][tid] + rr[2][tid] + rr[3][tid];
        const int slot = b * QTN + qt;            // 16 slots per channel
        const int i = tid & 3;
        const int c = h * 4 + i;
        if (tid < 4) part2[c * 16 + slot] = t;
        else         part2[2048 + c * 16 + slot] = t;
    }
}

// ---------------- Kernel 3: fused BN stats + normalize (16-slot) -----------
__global__ __launch_bounds__(256) void bn_norm_fused(
    float* __restrict__ y, const float* __restrict__ part2,
    const float* __restrict__ gamma, const float* __restrict__ beta)
{
    __shared__ float st[128];
    const int tid = threadIdx.x;
    if (tid < 128) {
        const int c = tid & 63;
        const float* p = part2 + (tid >> 6) * 2048 + c * 16;
        float s = 0.f;
        #pragma unroll
        for (int i = 0; i < 16; ++i) s += p[i];
        st[tid] = s;
    }
    __syncthreads();

    const int idx = blockIdx.x * 256 + tid;          // float4 index
    const int c0 = (idx & 15) * 4;
    float4 v = ((const float4*)y)[idx];
    const float n = 1.0f / NROWS;
    const float m0 = st[c0] * n,     m1 = st[c0 + 1] * n;
    const float m2 = st[c0 + 2] * n, m3 = st[c0 + 3] * n;
    const float r0 = rsqrtf(st[64 + c0] * n - m0 * m0 + 1e-5f);
    const float r1 = rsqrtf(st[65 + c0] * n - m1 * m1 + 1e-5f);
    const float r2 = rsqrtf(st[66 + c0] * n - m2 * m2 + 1e-5f);
    const float r3 = rsqrtf(st[67 + c0] * n - m3 * m3 + 1e-5f);
    float4 o;
    o.x = fmaf((v.x - m0) * r0, gamma[c0],     beta[c0]);
    o.y = fmaf((v.y - m1) * r1, gamma[c0 + 1], beta[c0 + 1]);
    o.z = fmaf((v.z - m2) * r2, gamma[c0 + 2], beta[c0 + 2]);
    o.w = fmaf((v.w - m3) * r3, gamma[c0 + 3], beta[c0 + 3]);
    ((float4*)y)[idx] = o;
}

// ---------------------------------------------------------------------------
extern "C" void kernel_launch(void* const* d_in, const int* in_sizes, int n_in,
                              void* d_out, int out_size, void* d_ws, size_t ws_size,
                              hipStream_t stream)
{
    const float* x     = (const float*)d_in[0];
    const float* Wq    = (const float*)d_in[1];
    const float* bq    = (const float*)d_in[2];
    const float* Wk    = (const float*)d_in[3];
    const float* bk    = (const float*)d_in[4];
    const float* Wv    = (const float*)d_in[5];
    const float* bv    = (const float*)d_in[6];
    const float* gamma = (const float*)d_in[7];
    const float* beta  = (const float*)d_in[8];
    float* out = (float*)d_out;

    float* ws = (float*)d_ws;
    float* Q  = ws;                  // 524288 floats (2 MB)
    float* KV = ws + 524288;         // 1048576 floats (4 MB)

    const size_t base = 524288 + 1048576;
    auto need = [](int kk) {
        return (size_t)(524288 + 1048576 + (size_t)kk * NQ * 5 + 4096 + 512) * 4;
    };

    int KS = 1;
    if (ws_size >= need(8))      KS = 8;
    else if (ws_size >= need(4)) KS = 4;
    else if (ws_size >= need(2)) KS = 2;

    float* accS  = ws + base;                        // KS*NQ*4 floats
    float* sumS  = accS + (size_t)KS * NQ * 4;       // KS*NQ floats
    float* part2 = sumS + (size_t)KS * NQ;           // 4096 floats
    unsigned int* cnt = (unsigned int*)(part2 + 4096);  // 256 uints

    qkv_kernel<<<NROWS / 4, 256, 0, stream>>>(x, Wq, bq, Wk, bk, Wv, bv, Q, KV, cnt);

    if (KS == 8)
        attn_kernel<8><<<8 * NGRP, 256, 0, stream>>>(Q, KV, x, out, accS, sumS, part2, cnt);
    else if (KS == 4)
        attn_kernel<4><<<4 * NGRP, 256, 0, stream>>>(Q, KV, x, out, accS, sumS, part2, cnt);
    else if (KS == 2)
        attn_kernel<2><<<2 * NGRP, 256, 0, stream>>>(Q, KV, x, out, accS, sumS, part2, cnt);
    else
        attn_kernel<1><<<1 * NGRP, 256, 0, stream>>>(Q, KV, x, out, accS, sumS, part2, cnt);

    bn_norm_fused<<<NROWS * DD / 1024, 256, 0, stream>>>(out, part2, gamma, beta);
}

// Round 16
// 118.142 us; speedup vs baseline: 2.5616x; 2.5616x over previous
//
#include <hip/hip_runtime.h>

#define BB 4
#define SS 2048
#define DD 64
#define HH 16
#define HDD 4
#define NBH (BB*HH)          // 64 (b,h) pairs
#define NROWS (BB*SS)        // 8192
#define LOG2E_HALF 0.7213475204444817f  // log2(e)*0.5 (1/sqrt(HD) folded into K)

// native 2-wide fp32 vector: compiler lowers fma on this to v_pk_fma_f32
// (gfx90a+ packed-FP32), inserting required hazard wait-states itself.
typedef float f32x2 __attribute__((ext_vector_type(2)));

#define CHKP 256             // KV pairs per LDS chunk (16 KB)
#define PPT  (CHKP/4)        // 64 pairs per thread per chunk
#define NCHK (SS/2/CHKP)     // 4 chunks
#define SLOTS 128            // BN partial slots per channel (4 b x 32 rowtiles)

// ---------------- Kernel 1: QKV projection + ReLU (R10 exact) --------------
__global__ __launch_bounds__(256) void qkv_kernel(
    const float* __restrict__ x,
    const float* __restrict__ Wq, const float* __restrict__ bq,
    const float* __restrict__ Wk, const float* __restrict__ bk,
    const float* __restrict__ Wv, const float* __restrict__ bv,
    float* __restrict__ Q, float* __restrict__ KV)
{
    __shared__ float xs[4 * 64];
    const int tid = threadIdx.x;
    const int row0 = blockIdx.x * 4;

    xs[tid] = x[(size_t)row0 * 64 + tid];
    __syncthreads();

    const int r = tid >> 6;
    const int c = tid & 63;
    const int row = row0 + r;
    const int b = row >> 11;
    const int s = row & (SS - 1);
    const float* xr = &xs[r * 64];

    float aq = bq[c], ak = bk[c], av = bv[c];
    #pragma unroll 16
    for (int k = 0; k < 64; ++k) {
        const float xv = xr[k];
        aq = fmaf(xv, Wq[k * 64 + c], aq);
        ak = fmaf(xv, Wk[k * 64 + c], ak);
        av = fmaf(xv, Wv[k * 64 + c], av);
    }
    aq = fmaxf(aq, 0.0f);
    ak = fmaxf(ak, 0.0f) * LOG2E_HALF;   // fold softmax scale+log2e into K
    av = fmaxf(av, 0.0f);

    const int h = c >> 2, hd = c & 3;
    const size_t bhs = ((size_t)(b * HH + h) * SS + s);
    Q[bhs * 4 + hd] = aq;

    const int p = s >> 1, po = s & 1;
    const size_t pb = ((size_t)(b * HH + h) * (SS / 2) + p) * 16;
    KV[pb + hd * 2 + po] = ak;
    KV[pb + 8 + hd * 2 + po] = av;
}

// ---------------- Kernel 2: attention + in-block combine + residual + BN ---
// 2048 blocks = (bh, rowtile of 64 rows). Thread = (row r = tid&63,
// keypart p = tid>>6). Wave-uniform p keeps LDS reads pure broadcast.
// Each thread: 1 row x SS/8 key-pairs (same total work/row as R10).
// KV streamed through LDS in 16 KB chunks (21 KB total -> 7 blocks/CU =
// 28 waves/CU). Epilogue combines the 4 key-partials per row via LDS
// (fixed order -> deterministic), applies softmax + residual, writes y once,
// and emits per-channel BN sum/sumsq. No atomics, no fences, no extra kernel.
__global__ __launch_bounds__(256) void attn_fused(
    const float* __restrict__ Qb, const float* __restrict__ KVb,
    const float* __restrict__ x, float* __restrict__ y,
    float* __restrict__ part2)
{
    __shared__ float4 kvs4[CHKP * 4];    // 16 KB
    __shared__ float red[4][64][5];      // 5 KB, stride-5 -> conflict-free
    const f32x2* kvs = (const f32x2*)kvs4;

    const int tid = threadIdx.x;
    const int bh = blockIdx.x >> 5;      // 0..63
    const int rt = blockIdx.x & 31;      // rowtile 0..31
    const int r  = tid & 63;
    const int p  = tid >> 6;             // keypart 0..3 (wave-uniform)
    const int qrow = rt * 64 + r;

    const float4 q4 = ((const float4*)Qb)[(size_t)bh * SS + qrow];
    const f32x2 qx = {q4.x, q4.x}, qy = {q4.y, q4.y};
    const f32x2 qz = {q4.z, q4.z}, qw = {q4.w, q4.w};

    f32x2 acx = {0.f, 0.f}, acy = {0.f, 0.f};
    f32x2 acz = {0.f, 0.f}, acw = {0.f, 0.f};
    f32x2 sm = {0.f, 0.f};

    const float4* kvg = (const float4*)(KVb + (size_t)bh * (SS / 2) * 16);

    for (int ch = 0; ch < NCHK; ++ch) {
        __syncthreads();                          // LDS reuse guard
        #pragma unroll
        for (int i = 0; i < CHKP * 4 / 256; ++i)  // 4 x float4 per thread
            kvs4[i * 256 + tid] = kvg[ch * CHKP * 4 + i * 256 + tid];
        __syncthreads();

        const f32x2* kp = kvs + (size_t)p * PPT * 8;
        #pragma unroll 2
        for (int j = 0; j < PPT; ++j) {
            const f32x2 kx = kp[j * 8 + 0];   // broadcast LDS reads
            const f32x2 ky = kp[j * 8 + 1];
            const f32x2 kz = kp[j * 8 + 2];
            const f32x2 kw = kp[j * 8 + 3];
            const f32x2 vx = kp[j * 8 + 4];
            const f32x2 vy = kp[j * 8 + 5];
            const f32x2 vz = kp[j * 8 + 6];
            const f32x2 vw = kp[j * 8 + 7];
            f32x2 s = qx * kx;
            s = __builtin_elementwise_fma(qy, ky, s);
            s = __builtin_elementwise_fma(qz, kz, s);
            s = __builtin_elementwise_fma(qw, kw, s);
            f32x2 e;
            e.x = __builtin_amdgcn_exp2f(s.x);
            e.y = __builtin_amdgcn_exp2f(s.y);
            sm += e;
            acx = __builtin_elementwise_fma(e, vx, acx);
            acy = __builtin_elementwise_fma(e, vy, acy);
            acz = __builtin_elementwise_fma(e, vz, acz);
            acw = __builtin_elementwise_fma(e, vw, acw);
        }
    }

    // ---- stash this thread's key-partial (acc, sum) ----
    red[p][r][0] = acx.x + acx.y;
    red[p][r][1] = acy.x + acy.y;
    red[p][r][2] = acz.x + acz.y;
    red[p][r][3] = acw.x + acw.y;
    red[p][r][4] = sm.x + sm.y;
    __syncthreads();
    if (tid >= 64) return;               // wave 0 finishes the block

    // ---- combine 4 key-partials per row (fixed order -> deterministic) ----
    float4 a;
    a.x = red[0][r][0] + red[1][r][0] + red[2][r][0] + red[3][r][0];
    a.y = red[0][r][1] + red[1][r][1] + red[2][r][1] + red[3][r][1];
    a.z = red[0][r][2] + red[1][r][2] + red[2][r][2] + red[3][r][2];
    a.w = red[0][r][3] + red[1][r][3] + red[2][r][3] + red[3][r][3];
    const float s = red[0][r][4] + red[1][r][4] + red[2][r][4] + red[3][r][4];
    const float inv = 1.0f / s;

    const int b = bh >> 4, h = bh & 15;
    const size_t o = ((size_t)(b * SS + qrow)) * DD + h * HDD;
    const float4 xr = *(const float4*)(x + o);
    float4 out;
    out.x = fmaf(a.x, inv, xr.x);
    out.y = fmaf(a.y, inv, xr.y);
    out.z = fmaf(a.z, inv, xr.z);
    out.w = fmaf(a.w, inv, xr.w);
    *(float4*)(y + o) = out;

    // ---- per-channel BN partials over this block's 64 rows ----
    float vv[8] = {out.x, out.y, out.z, out.w,
                   out.x * out.x, out.y * out.y, out.z * out.z, out.w * out.w};
    #pragma unroll
    for (int i = 0; i < 8; ++i) {
        float t = vv[i];
        #pragma unroll
        for (int off = 32; off > 0; off >>= 1) t += __shfl_down(t, off);
        vv[i] = t;
    }
    if (r == 0) {
        const int slot = b * 32 + rt;            // 128 slots per channel
        const int c0 = h * 4;
        #pragma unroll
        for (int i = 0; i < 4; ++i) {
            part2[(c0 + i) * SLOTS + slot] = vv[i];
            part2[64 * SLOTS + (c0 + i) * SLOTS + slot] = vv[4 + i];
        }
    }
}

// ---------------- Kernel 3: fused BN stats + normalize ---------------------
// Each block redundantly reduces the 64 KB partial array (L2-hot), then
// normalizes its 1024-element float4 slice of y in place.
__global__ __launch_bounds__(256) void bn_norm_fused(
    float* __restrict__ y, const float* __restrict__ part2,
    const float* __restrict__ gamma, const float* __restrict__ beta)
{
    __shared__ float st[128];
    const int tid = threadIdx.x;
    if (tid < 128) {
        const int c = tid & 63;
        const float* p = part2 + (tid >> 6) * (64 * SLOTS) + c * SLOTS;
        float s = 0.f;
        #pragma unroll 8
        for (int i = 0; i < SLOTS; ++i) s += p[i];
        st[tid] = s;
    }
    __syncthreads();

    const int idx = blockIdx.x * 256 + tid;          // float4 index
    const int c0 = (idx & 15) * 4;
    float4 v = ((const float4*)y)[idx];
    const float n = 1.0f / NROWS;
    const float m0 = st[c0] * n,     m1 = st[c0 + 1] * n;
    const float m2 = st[c0 + 2] * n, m3 = st[c0 + 3] * n;
    const float r0 = rsqrtf(st[64 + c0] * n - m0 * m0 + 1e-5f);
    const float r1 = rsqrtf(st[65 + c0] * n - m1 * m1 + 1e-5f);
    const float r2 = rsqrtf(st[66 + c0] * n - m2 * m2 + 1e-5f);
    const float r3 = rsqrtf(st[67 + c0] * n - m3 * m3 + 1e-5f);
    float4 o;
    o.x = fmaf((v.x - m0) * r0, gamma[c0],     beta[c0]);
    o.y = fmaf((v.y - m1) * r1, gamma[c0 + 1], beta[c0 + 1]);
    o.z = fmaf((v.z - m2) * r2, gamma[c0 + 2], beta[c0 + 2]);
    o.w = fmaf((v.w - m3) * r3, gamma[c0 + 3], beta[c0 + 3]);
    ((float4*)y)[idx] = o;
}

// ---------------------------------------------------------------------------
extern "C" void kernel_launch(void* const* d_in, const int* in_sizes, int n_in,
                              void* d_out, int out_size, void* d_ws, size_t ws_size,
                              hipStream_t stream)
{
    const float* x     = (const float*)d_in[0];
    const float* Wq    = (const float*)d_in[1];
    const float* bq    = (const float*)d_in[2];
    const float* Wk    = (const float*)d_in[3];
    const float* bk    = (const float*)d_in[4];
    const float* Wv    = (const float*)d_in[5];
    const float* bv    = (const float*)d_in[6];
    const float* gamma = (const float*)d_in[7];
    const float* beta  = (const float*)d_in[8];
    float* out = (float*)d_out;

    float* ws    = (float*)d_ws;
    float* Q     = ws;                   // 524288 floats (2 MB)
    float* KV    = ws + 524288;          // 1048576 floats (4 MB)
    float* part2 = ws + 1572864;         // 2*64*128 = 16384 floats (64 KB)

    qkv_kernel<<<NROWS / 4, 256, 0, stream>>>(x, Wq, bq, Wk, bk, Wv, bv, Q, KV);
    attn_fused<<<NBH * 32, 256, 0, stream>>>(Q, KV, x, out, part2);
    bn_norm_fused<<<NROWS * DD / 1024, 256, 0, stream>>>(out, part2, gamma, beta);
}

// Round 17
// 110.076 us; speedup vs baseline: 2.7493x; 1.0733x over previous
//
#include <hip/hip_runtime.h>

#define BB 4
#define SS 2048
#define DD 64
#define HH 16
#define HDD 4
#define NBH (BB*HH)          // 64 (b,h) pairs
#define NROWS (BB*SS)        // 8192
#define NQ (NBH*SS)          // 131072 query rows
#define QTILES 8             // SS/256 (for combine kernel)
#define LOG2E_HALF 0.7213475204444817f  // log2(e)*0.5 (1/sqrt(HD) folded into K)

// native 2-wide fp32 vector: compiler lowers fma on this to v_pk_fma_f32
// (gfx90a+ packed-FP32), inserting required hazard wait-states itself.
typedef float f32x2 __attribute__((ext_vector_type(2)));

// ---------------- Kernel 1: QKV projection + ReLU (R10 exact) --------------
__global__ __launch_bounds__(256) void qkv_kernel(
    const float* __restrict__ x,
    const float* __restrict__ Wq, const float* __restrict__ bq,
    const float* __restrict__ Wk, const float* __restrict__ bk,
    const float* __restrict__ Wv, const float* __restrict__ bv,
    float* __restrict__ Q, float* __restrict__ KV)
{
    __shared__ float xs[4 * 64];
    const int tid = threadIdx.x;
    const int row0 = blockIdx.x * 4;

    xs[tid] = x[(size_t)row0 * 64 + tid];
    __syncthreads();

    const int r = tid >> 6;
    const int c = tid & 63;
    const int row = row0 + r;
    const int b = row >> 11;
    const int s = row & (SS - 1);
    const float* xr = &xs[r * 64];

    float aq = bq[c], ak = bk[c], av = bv[c];
    #pragma unroll 16
    for (int k = 0; k < 64; ++k) {
        const float xv = xr[k];
        aq = fmaf(xv, Wq[k * 64 + c], aq);
        ak = fmaf(xv, Wk[k * 64 + c], ak);
        av = fmaf(xv, Wv[k * 64 + c], av);
    }
    aq = fmaxf(aq, 0.0f);
    ak = fmaxf(ak, 0.0f) * LOG2E_HALF;   // fold softmax scale+log2e into K
    av = fmaxf(av, 0.0f);

    const int h = c >> 2, hd = c & 3;
    const size_t bhs = ((size_t)(b * HH + h) * SS + s);
    Q[bhs * 4 + hd] = aq;

    const int p = s >> 1, po = s & 1;
    const size_t pb = ((size_t)(b * HH + h) * (SS / 2) + p) * 16;
    KV[pb + hd * 2 + po] = ak;
    KV[pb + 8 + hd * 2 + po] = av;
}

// ---------------- Kernel 2: attention (R10 + unroll 4) ---------------------
// LDS-staged KV chunk (8 KB at KSPLIT=8), broadcast reads, packed fp32,
// hardware v_exp_f32, no max-subtraction (relu'd inputs, HD=4: scores
// bounded, exp2 safe). Single change vs R10: pairs-loop unroll 2 -> 4,
// giving the scheduler 4 independent dot->exp->PV chains to interleave
// (cross-round accounting shows the loop is dependency-stall-bound at
// ~5 cyc/instr; never tested with hardware exp at depth 4 -- R7's unroll-4
// was confounded with the bad libm poly).
template<int KSPLIT, int QROWS, bool DIRECT>
__global__ __launch_bounds__(256) void attn_kernel(
    const float* __restrict__ Qb, const float* __restrict__ KVb,
    const float* __restrict__ x, float* __restrict__ y,
    float* __restrict__ accS, float* __restrict__ sumS)
{
    constexpr int QT = SS / (256 * QROWS);   // q-tiles per bh
    constexpr int PAIRS = SS / 2 / KSPLIT;
    __shared__ float4 kvs4[PAIRS * 4];       // PAIRS*64 bytes
    const f32x2* kvs = (const f32x2*)kvs4;

    const int tid = threadIdx.x;
    int blk = blockIdx.x;
    const int ks = blk / (NBH * QT);
    blk -= ks * (NBH * QT);
    const int bh = blk / QT;
    const int qt = blk - bh * QT;

    const float4* kvg = (const float4*)(KVb + ((size_t)bh * (SS / 2) + (size_t)ks * PAIRS) * 16);
    #pragma unroll
    for (int i = 0; i < PAIRS * 4 / 256; ++i)
        kvs4[i * 256 + tid] = kvg[i * 256 + tid];

    f32x2 qx[QROWS], qy[QROWS], qz[QROWS], qw[QROWS];
    #pragma unroll
    for (int r = 0; r < QROWS; ++r) {
        const int qrow = qt * (256 * QROWS) + r * 256 + tid;
        const float4 q = ((const float4*)Qb)[(size_t)bh * SS + qrow];
        qx[r] = {q.x, q.x}; qy[r] = {q.y, q.y};
        qz[r] = {q.z, q.z}; qw[r] = {q.w, q.w};
    }

    f32x2 acx[QROWS], acy[QROWS], acz[QROWS], acw[QROWS], sm[QROWS];
    #pragma unroll
    for (int r = 0; r < QROWS; ++r) {
        acx[r] = {0.f, 0.f}; acy[r] = {0.f, 0.f};
        acz[r] = {0.f, 0.f}; acw[r] = {0.f, 0.f};
        sm[r] = {0.f, 0.f};
    }

    __syncthreads();

    #pragma unroll 4
    for (int j = 0; j < PAIRS; ++j) {
        const f32x2 kx = kvs[j * 8 + 0];   // broadcast LDS reads
        const f32x2 ky = kvs[j * 8 + 1];
        const f32x2 kz = kvs[j * 8 + 2];
        const f32x2 kw = kvs[j * 8 + 3];
        const f32x2 vx = kvs[j * 8 + 4];
        const f32x2 vy = kvs[j * 8 + 5];
        const f32x2 vz = kvs[j * 8 + 6];
        const f32x2 vw = kvs[j * 8 + 7];
        #pragma unroll
        for (int r = 0; r < QROWS; ++r) {
            f32x2 s = qx[r] * kx;
            s = __builtin_elementwise_fma(qy[r], ky, s);
            s = __builtin_elementwise_fma(qz[r], kz, s);
            s = __builtin_elementwise_fma(qw[r], kw, s);
            f32x2 e;
            e.x = __builtin_amdgcn_exp2f(s.x);
            e.y = __builtin_amdgcn_exp2f(s.y);
            sm[r] += e;
            acx[r] = __builtin_elementwise_fma(e, vx, acx[r]);
            acy[r] = __builtin_elementwise_fma(e, vy, acy[r]);
            acz[r] = __builtin_elementwise_fma(e, vz, acz[r]);
            acw[r] = __builtin_elementwise_fma(e, vw, acw[r]);
        }
    }

    #pragma unroll
    for (int r = 0; r < QROWS; ++r) {
        const int qrow = qt * (256 * QROWS) + r * 256 + tid;
        const float sum = sm[r].x + sm[r].y;
        float4 acc = {acx[r].x + acx[r].y, acy[r].x + acy[r].y,
                      acz[r].x + acz[r].y, acw[r].x + acw[r].y};
        if (DIRECT) {
            const float inv = 1.0f / sum;
            const int b = bh >> 4, h = bh & 15;
            const size_t o = ((size_t)(b * SS + qrow)) * DD + h * HDD;
            const float4 xr = *(const float4*)(x + o);
            float4 out;
            out.x = fmaf(acc.x, inv, xr.x);
            out.y = fmaf(acc.y, inv, xr.y);
            out.z = fmaf(acc.z, inv, xr.z);
            out.w = fmaf(acc.w, inv, xr.w);
            *(float4*)(y + o) = out;
        } else {
            const size_t qi = (size_t)ks * NQ + (size_t)bh * SS + qrow;
            ((float4*)accS)[qi] = acc;
            sumS[qi] = sum;
        }
    }
}

// ---------------- Kernel 3: combine partials + residual + BN partials ------
template<int KSPLIT>
__global__ __launch_bounds__(256) void combine_bn(
    const float* __restrict__ accS, const float* __restrict__ sumS,
    const float* __restrict__ x, float* __restrict__ y,
    float* __restrict__ part2)
{
    __shared__ float r[4][8];
    const int tid = threadIdx.x;
    const int bh = blockIdx.x >> 3;
    const int qt = blockIdx.x & 7;
    const int qrow = qt * 256 + tid;
    const size_t qi = (size_t)bh * SS + qrow;

    float4 a = ((const float4*)accS)[qi];
    float s = sumS[qi];
    #pragma unroll
    for (int k = 1; k < KSPLIT; ++k) {
        const float4 a2 = ((const float4*)accS)[(size_t)k * NQ + qi];
        a.x += a2.x; a.y += a2.y; a.z += a2.z; a.w += a2.w;
        s += sumS[(size_t)k * NQ + qi];
    }
    const float inv = 1.0f / s;
    const int b = bh >> 4, h = bh & 15;
    const size_t o = ((size_t)(b * SS + qrow)) * DD + h * HDD;
    const float4 xr = *(const float4*)(x + o);
    float4 out;
    out.x = fmaf(a.x, inv, xr.x);
    out.y = fmaf(a.y, inv, xr.y);
    out.z = fmaf(a.z, inv, xr.z);
    out.w = fmaf(a.w, inv, xr.w);
    *(float4*)(y + o) = out;

    float v[8] = {out.x, out.y, out.z, out.w,
                  out.x * out.x, out.y * out.y, out.z * out.z, out.w * out.w};
    #pragma unroll
    for (int i = 0; i < 8; ++i) {
        float t = v[i];
        for (int off = 32; off > 0; off >>= 1) t += __shfl_down(t, off);
        v[i] = t;
    }
    const int wid = tid >> 6;
    if ((tid & 63) == 0) {
        #pragma unroll
        for (int i = 0; i < 8; ++i) r[wid][i] = v[i];
    }
    __syncthreads();
    if (tid < 8) {
        const float t = r[0][tid] + r[1][tid] + r[2][tid] + r[3][tid];
        const int slot = b * 8 + qt;
        const int i = tid & 3;
        const int c = h * 4 + i;
        if (tid < 4) part2[c * 32 + slot] = t;
        else         part2[2048 + c * 32 + slot] = t;
    }
}

// ---------------- Kernel 4: fused BN stats + normalize ---------------------
__global__ __launch_bounds__(256) void bn_norm_fused(
    float* __restrict__ y, const float* __restrict__ part2,
    const float* __restrict__ gamma, const float* __restrict__ beta)
{
    __shared__ float st[128];
    const int tid = threadIdx.x;
    if (tid < 128) {
        const int c = tid & 63;
        const float* p = part2 + (tid >> 6) * 2048 + c * 32;
        float s = 0.f;
        #pragma unroll
        for (int i = 0; i < 32; ++i) s += p[i];
        st[tid] = s;
    }
    __syncthreads();

    const int idx = blockIdx.x * 256 + tid;          // float4 index
    const int c0 = (idx & 15) * 4;
    float4 v = ((const float4*)y)[idx];
    const float n = 1.0f / NROWS;
    const float m0 = st[c0] * n,     m1 = st[c0 + 1] * n;
    const float m2 = st[c0 + 2] * n, m3 = st[c0 + 3] * n;
    const float r0 = rsqrtf(st[64 + c0] * n - m0 * m0 + 1e-5f);
    const float r1 = rsqrtf(st[65 + c0] * n - m1 * m1 + 1e-5f);
    const float r2 = rsqrtf(st[66 + c0] * n - m2 * m2 + 1e-5f);
    const float r3 = rsqrtf(st[67 + c0] * n - m3 * m3 + 1e-5f);
    float4 o;
    o.x = fmaf((v.x - m0) * r0, gamma[c0],     beta[c0]);
    o.y = fmaf((v.y - m1) * r1, gamma[c0 + 1], beta[c0 + 1]);
    o.z = fmaf((v.z - m2) * r2, gamma[c0 + 2], beta[c0 + 2]);
    o.w = fmaf((v.w - m3) * r3, gamma[c0 + 3], beta[c0 + 3]);
    ((float4*)y)[idx] = o;
}

// ---------------- Fallback BN reduce (tiny-workspace path) -----------------
__global__ __launch_bounds__(256) void bn_reduce1(
    const float* __restrict__ y, float* __restrict__ part)
{
    __shared__ float ls[256], ls2[256];
    const int tid = threadIdx.x;
    const int c = tid & 63;
    const int rg = tid >> 6;
    const int row0 = blockIdx.x * 32 + rg * 8;
    float s = 0.0f, s2 = 0.0f;
    #pragma unroll
    for (int i = 0; i < 8; ++i) {
        const float v = y[(size_t)(row0 + i) * 64 + c];
        s += v;
        s2 = fmaf(v, v, s2);
    }
    ls[tid] = s; ls2[tid] = s2;
    __syncthreads();
    if (rg == 0) {
        part[blockIdx.x * 64 + c] = ls[c] + ls[64 + c] + ls[128 + c] + ls[192 + c];
        part[256 * 64 + blockIdx.x * 64 + c] = ls2[c] + ls2[64 + c] + ls2[128 + c] + ls2[192 + c];
    }
}

__global__ __launch_bounds__(256) void bn_reduce2(
    const float* __restrict__ part, float* __restrict__ stats)
{
    __shared__ float ls[256], ls2[256];
    const int tid = threadIdx.x;
    const int c = tid & 63;
    const int pg = tid >> 6;
    float s = 0.0f, s2 = 0.0f;
    for (int i = pg; i < 256; i += 4) {
        s  += part[i * 64 + c];
        s2 += part[256 * 64 + i * 64 + c];
    }
    ls[tid] = s; ls2[tid] = s2;
    __syncthreads();
    if (pg == 0) {
        const float ts  = ls[c]  + ls[64 + c]  + ls[128 + c]  + ls[192 + c];
        const float ts2 = ls2[c] + ls2[64 + c] + ls2[128 + c] + ls2[192 + c];
        const float mean = ts * (1.0f / NROWS);
        const float var  = ts2 * (1.0f / NROWS) - mean * mean;
        stats[c] = mean;
        stats[64 + c] = rsqrtf(var + 1e-5f);
    }
}

__global__ __launch_bounds__(256) void bn_norm(
    float* __restrict__ y, const float* __restrict__ stats,
    const float* __restrict__ gamma, const float* __restrict__ beta)
{
    const int idx = blockIdx.x * 256 + threadIdx.x;
    const int c = idx & 63;
    const float v = y[idx];
    y[idx] = fmaf((v - stats[c]) * stats[64 + c], gamma[c], beta[c]);
}

// ---------------------------------------------------------------------------
extern "C" void kernel_launch(void* const* d_in, const int* in_sizes, int n_in,
                              void* d_out, int out_size, void* d_ws, size_t ws_size,
                              hipStream_t stream)
{
    const float* x     = (const float*)d_in[0];
    const float* Wq    = (const float*)d_in[1];
    const float* bq    = (const float*)d_in[2];
    const float* Wk    = (const float*)d_in[3];
    const float* bk    = (const float*)d_in[4];
    const float* Wv    = (const float*)d_in[5];
    const float* bv    = (const float*)d_in[6];
    const float* gamma = (const float*)d_in[7];
    const float* beta  = (const float*)d_in[8];
    float* out = (float*)d_out;

    float* ws = (float*)d_ws;
    float* Q  = ws;                  // 524288 floats (2 MB)
    float* KV = ws + 524288;         // 1048576 floats (4 MB)

    qkv_kernel<<<NROWS / 4, 256, 0, stream>>>(x, Wq, bq, Wk, bk, Wv, bv, Q, KV);

    const size_t base = 524288 + 1048576;
    auto need = [](int kk) {
        return (size_t)(524288 + 1048576 + (size_t)kk * NQ * 5 + 4096 + 128) * 4;
    };
    constexpr int QR = 2;                      // query rows per thread
    constexpr int QT = SS / (256 * QR);        // 4 q-tiles per bh

    if (ws_size >= need(8)) {
        // 8-way key split: 2048 blocks, 8 KB LDS KV chunk per block
        float* accS  = ws + base;
        float* sumS  = accS + (size_t)8 * NQ * 4;
        float* part2 = sumS + (size_t)8 * NQ;
        attn_kernel<8, QR, false><<<8 * NBH * QT, 256, 0, stream>>>(Q, KV, x, out, accS, sumS);
        combine_bn<8><<<NBH * QTILES, 256, 0, stream>>>(accS, sumS, x, out, part2);
        bn_norm_fused<<<NROWS * DD / 1024, 256, 0, stream>>>(out, part2, gamma, beta);
    } else if (ws_size >= need(4)) {
        float* accS  = ws + base;
        float* sumS  = accS + (size_t)4 * NQ * 4;
        float* part2 = sumS + (size_t)4 * NQ;
        attn_kernel<4, QR, false><<<4 * NBH * QT, 256, 0, stream>>>(Q, KV, x, out, accS, sumS);
        combine_bn<4><<<NBH * QTILES, 256, 0, stream>>>(accS, sumS, x, out, part2);
        bn_norm_fused<<<NROWS * DD / 1024, 256, 0, stream>>>(out, part2, gamma, beta);
    } else if (ws_size >= need(2)) {
        float* accS  = ws + base;
        float* sumS  = accS + (size_t)2 * NQ * 4;
        float* part2 = sumS + (size_t)2 * NQ;
        attn_kernel<2, QR, false><<<2 * NBH * QT, 256, 0, stream>>>(Q, KV, x, out, accS, sumS);
        combine_bn<2><<<NBH * QTILES, 256, 0, stream>>>(accS, sumS, x, out, part2);
        bn_norm_fused<<<NROWS * DD / 1024, 256, 0, stream>>>(out, part2, gamma, beta);
    } else {
        float* part  = ws + base;                      // 32768 floats
        float* stats = part + 32768;                   // 128
        attn_kernel<1, QR, true><<<NBH * QT, 256, 0, stream>>>(Q, KV, x, out, nullptr, nullptr);
        bn_reduce1<<<256, 256, 0, stream>>>(out, part);
        bn_reduce2<<<1, 256, 0, stream>>>(part, stats);
        bn_norm<<<NROWS * DD / 256, 256, 0, stream>>>(out, stats, gamma, beta);
    }
}